// Round 4
// baseline (358.068 us; speedup 1.0000x reference)
//
#include <hip/hip_runtime.h>
#include <hip/hip_fp16.h>

#define B_ 2
#define S_ 2048
#define D_ 2048
#define H_ 32
#define KV_ 8
#define HD_ 64

typedef unsigned short bf16_t;
typedef __attribute__((ext_vector_type(8))) short short8;
typedef __attribute__((ext_vector_type(4))) float floatx4;
typedef __attribute__((ext_vector_type(16))) float floatx16;

__device__ __forceinline__ bf16_t f2bf(float f) {
  union { float f; unsigned u; } c; c.f = f;
  unsigned u = c.u;
  u += 0x7fffu + ((u >> 16) & 1u);          // round-to-nearest-even
  return (bf16_t)(u >> 16);
}

__device__ __forceinline__ unsigned pk_bf16(float a, float b) {
#if __has_builtin(__builtin_amdgcn_cvt_pk_bf16_f32)
  auto v = __builtin_amdgcn_cvt_pk_bf16_f32(a, b);
  unsigned u; __builtin_memcpy(&u, &v, 4); return u;
#else
  return (unsigned)f2bf(a) | ((unsigned)f2bf(b) << 16);
#endif
}

__device__ __forceinline__ float fexp2(float x) {
#if __has_builtin(__builtin_amdgcn_exp2f)
  return __builtin_amdgcn_exp2f(x);
#else
  return exp2f(x);
#endif
}

__device__ __forceinline__ void load_lds16(const void* g, void* l) {
  __builtin_amdgcn_global_load_lds(
      (const __attribute__((address_space(1))) void*)g,
      (__attribute__((address_space(3))) void*)l, 16, 0, 0);
}

// ---------------- prep: fp32->bf16 casts + packed fp16 rope table ----------------
__device__ __forceinline__ void cvt4(const float* __restrict__ in,
                                     bf16_t* __restrict__ out, int i) {
  float4 v = ((const float4*)in)[i];
  ushort4 o;
  o.x = f2bf(v.x); o.y = f2bf(v.y); o.z = f2bf(v.z); o.w = f2bf(v.w);
  ((ushort4*)out)[i] = o;
}

__global__ __launch_bounds__(256) void prep(
    const float* __restrict__ x, bf16_t* __restrict__ xb,
    const float* __restrict__ wqkv, bf16_t* __restrict__ wqkvb,
    const float* __restrict__ wout, bf16_t* __restrict__ woutb,
    const float* __restrict__ cs, const float* __restrict__ sn,
    unsigned* __restrict__ tab) {
  const int bid = blockIdx.x;
  if (bid < 8192) {
    cvt4(x, xb, bid * 256 + threadIdx.x);
  } else if (bid < 14336) {
    cvt4(wqkv, wqkvb, (bid - 8192) * 256 + threadIdx.x);
  } else if (bid < 18432) {
    cvt4(wout, woutb, (bid - 14336) * 256 + threadIdx.x);
  } else {
    const int i = (bid - 18432) * 256 + threadIdx.x;   // 131072 entries
    __half2 h = __floats2half2_rn(cs[i], sn[i]);
    unsigned u; __builtin_memcpy(&u, &h, 4);
    tab[i] = u;
  }
}

// ---------------- bf16 GEMM: C[M,N] = A[M,K] * B^T (f32 out) ----------------
__global__ __launch_bounds__(256) void gemm_bt(
    const bf16_t* __restrict__ A, const bf16_t* __restrict__ Bm,
    float* __restrict__ C, int M, int N, int K) {
  __shared__ __attribute__((aligned(16))) bf16_t As[128 * 32];
  __shared__ __attribute__((aligned(16))) bf16_t Bs[128 * 32];
  const int tid = threadIdx.x;
  const int lane = tid & 63;
  const int wave = tid >> 6;
  const int bm = blockIdx.y * 128, bn = blockIdx.x * 128;
  const int wm = (wave >> 1) * 64, wn = (wave & 1) * 64;
  const int lr = lane & 15, quad = lane >> 4;

  floatx4 acc[4][4] = {};

  const int t0 = tid, t1 = tid + 256;
  const int r0 = t0 >> 2, c0 = (t0 & 3) * 8;
  const int r1 = t1 >> 2, c1 = (t1 & 3) * 8;

  const bf16_t* Ab = A + (size_t)bm * K;
  const bf16_t* Bb = Bm + (size_t)bn * K;

  for (int k0 = 0; k0 < K; k0 += 32) {
    __syncthreads();
    load_lds16(Ab + (size_t)r0 * K + k0 + c0, &As[t0 * 8]);
    load_lds16(Ab + (size_t)r1 * K + k0 + c1, &As[t1 * 8]);
    load_lds16(Bb + (size_t)r0 * K + k0 + c0, &Bs[t0 * 8]);
    load_lds16(Bb + (size_t)r1 * K + k0 + c1, &Bs[t1 * 8]);
    __syncthreads();

    short8 af[4], bfr[4];
#pragma unroll
    for (int i = 0; i < 4; i++) {
      af[i]  = *(const short8*)&As[(wm + i * 16 + lr) * 32 + quad * 8];
      bfr[i] = *(const short8*)&Bs[(wn + i * 16 + lr) * 32 + quad * 8];
    }
#pragma unroll
    for (int mi = 0; mi < 4; mi++)
#pragma unroll
      for (int ni = 0; ni < 4; ni++)
        acc[mi][ni] = __builtin_amdgcn_mfma_f32_16x16x32_bf16(af[mi], bfr[ni], acc[mi][ni], 0, 0, 0);
  }

#pragma unroll
  for (int mi = 0; mi < 4; mi++) {
    const int row = bm + wm + mi * 16 + quad * 4;
#pragma unroll
    for (int ni = 0; ni < 4; ni++) {
      const int col = bn + wn + ni * 16 + lr;
      float* cp = C + (size_t)row * N + col;
#pragma unroll
      for (int r = 0; r < 4; r++) cp[(size_t)r * N] = acc[mi][ni][r];
    }
  }
}

// ---------------- fused QKV GEMM + RoPE (fp16 table) + repack ----------------
__global__ __launch_bounds__(256, 4) void gemm_qkv(
    const bf16_t* __restrict__ A, const bf16_t* __restrict__ Bm,
    const unsigned* __restrict__ tab,
    bf16_t* __restrict__ q, bf16_t* __restrict__ k, bf16_t* __restrict__ vt) {
  const int K = 2048;
  __shared__ __attribute__((aligned(16))) bf16_t As[128 * 32];
  __shared__ __attribute__((aligned(16))) bf16_t Bs[128 * 32];
  __shared__ __attribute__((aligned(16))) bf16_t Ts[4][32 * 72];  // V transpose (2-pass)
  const int tid = threadIdx.x;
  const int lane = tid & 63;
  const int wave = tid >> 6;
  const int bm = blockIdx.y * 128, bn = blockIdx.x * 128;
  const int wm = (wave >> 1) * 64, wn = (wave & 1) * 64;
  const int lr = lane & 15, quad = lane >> 4;

  floatx4 acc[4][4] = {};

  const int t0 = tid, t1 = tid + 256;
  const int r0 = t0 >> 2, c0 = (t0 & 3) * 8;
  const int r1 = t1 >> 2, c1 = (t1 & 3) * 8;

  const bf16_t* Ab = A + (size_t)bm * K;
  const bf16_t* Bb = Bm + (size_t)bn * K;

  for (int k0 = 0; k0 < K; k0 += 32) {
    __syncthreads();
    load_lds16(Ab + (size_t)r0 * K + k0 + c0, &As[t0 * 8]);
    load_lds16(Ab + (size_t)r1 * K + k0 + c1, &As[t1 * 8]);
    load_lds16(Bb + (size_t)r0 * K + k0 + c0, &Bs[t0 * 8]);
    load_lds16(Bb + (size_t)r1 * K + k0 + c1, &Bs[t1 * 8]);
    __syncthreads();

    short8 af[4], bfr[4];
#pragma unroll
    for (int i = 0; i < 4; i++) {
      af[i]  = *(const short8*)&As[(wm + i * 16 + lr) * 32 + quad * 8];
      bfr[i] = *(const short8*)&Bs[(wn + i * 16 + lr) * 32 + quad * 8];
    }
#pragma unroll
    for (int mi = 0; mi < 4; mi++)
#pragma unroll
      for (int ni = 0; ni < 4; ni++)
        acc[mi][ni] = __builtin_amdgcn_mfma_f32_16x16x32_bf16(af[mi], bfr[ni], acc[mi][ni], 0, 0, 0);
  }

  const int f0 = bn + wn;              // wave-uniform feature base (multiple of 64)
  const int srow0 = bm + wm;
  const int bb = srow0 >> 11, s0 = srow0 & 2047;

  if (f0 < 2560) {                     // Q or K head: in-register rope
    const bool isq = (f0 < 2048);
    const float scale = isq ? 0.18033688011f : 1.0f;   // 0.125 * log2(e)
    bf16_t* dst = isq ? (q + (size_t)(bb * H_ + (f0 >> 6)) * S_ * HD_)
                      : (k + (size_t)(bb * KV_ + ((f0 - 2048) >> 6)) * S_ * HD_);
#pragma unroll
    for (int mi = 0; mi < 4; mi++) {
#pragma unroll
      for (int r = 0; r < 4; r++) {
        const int sr = s0 + mi * 16 + quad * 4 + r;
        const unsigned* tp = tab + (size_t)sr * HD_;
        bf16_t* drow = dst + (size_t)sr * HD_;
#pragma unroll
        for (int ni = 0; ni < 4; ni++) {
          const int d = ni * 16 + lr;
          const unsigned w = tp[d];
          __half2 h2; __builtin_memcpy(&h2, &w, 4);
          const float2 cf = __half22float2(h2);
          const float t = acc[mi][ni][r];
          const float oth = acc[mi][ni ^ 2][r];
          const float rot = (ni < 2) ? -oth : oth;   // d<32 iff ni<2
          drow[d] = f2bf((t * cf.x + rot * cf.y) * scale);
        }
      }
    }
  } else {                             // V head: 2-pass transpose via 9 KB/wave LDS
    const int hv = (f0 - 2560) >> 6;
    bf16_t* ts = Ts[wave];
    const int rl = lane >> 1, hf = lane & 1;
#pragma unroll
    for (int p = 0; p < 2; p++) {
#pragma unroll
      for (int nn = 0; nn < 2; nn++) {
        const int ni = 2 * p + nn;
#pragma unroll
        for (int mi = 0; mi < 4; mi++) {
          uint2 pw;
          pw.x = pk_bf16(acc[mi][ni][0], acc[mi][ni][1]);
          pw.y = pk_bf16(acc[mi][ni][2], acc[mi][ni][3]);
          *(uint2*)&ts[(nn * 16 + lr) * 72 + mi * 16 + quad * 4] = pw;
        }
      }
      // same-wave RAW/WAR: DS pipe is in-order per wave, compiler emits lgkmcnt
      bf16_t* vrow = vt + ((size_t)(bb * KV_ + hv) * HD_ + p * 32 + rl) * S_ + s0 + hf * 32;
#pragma unroll
      for (int j = 0; j < 4; j++)
        *(short8*)(vrow + j * 8) = *(const short8*)&ts[rl * 72 + hf * 32 + j * 8];
    }
  }
}

// ---------------- flash attention v5: barrier-free, LDS-free ----------------
// One 32-q-row tile per independent 64-thread block. K/V fragments are loaded
// directly from global (L2-resident: K+V = 512 KB per kv-head, shared by 4
// q-heads) as MFMA operands. No LDS, no __syncthreads, no bank conflicts --
// occupancy is VGPR-bound (~4 waves/SIMD) and all stalls hide via TLP.
// XCD swizzle: XCD x owns bh in [8x, 8x+8) => ~1 MB KV working set per XCD L2.
// Heavy ranks dispatch first (global LPT).

// halves-exchange: x = [a.lo | b.lo], y = [a.hi | b.hi] (lanes 0-31 | 32-63)
__device__ __forceinline__ void hswap(unsigned a, unsigned b, unsigned& x, unsigned& y) {
#if __has_builtin(__builtin_amdgcn_permlane32_swap)
  auto r = __builtin_amdgcn_permlane32_swap(a, b, false, false);
  x = (unsigned)r[0]; y = (unsigned)r[1];
#else
  const unsigned pa = (unsigned)__shfl_xor((int)a, 32, 64);
  const unsigned pb = (unsigned)__shfl_xor((int)b, 32, 64);
  const bool hi = (threadIdx.x & 32) != 0;
  x = hi ? pb : a;
  y = hi ? b : pa;
#endif
}

// one 32-k tile of P in lane regs -> two PV B-fragments (k-slices of 16)
__device__ __forceinline__ void build_pfrag(const floatx16& p, short8& f0, short8& f1) {
  unsigned w[8];
  const unsigned c01 = pk_bf16(p[0], p[1]);
  const unsigned c45 = pk_bf16(p[4], p[5]);
  const unsigned c23 = pk_bf16(p[2], p[3]);
  const unsigned c67 = pk_bf16(p[6], p[7]);
  hswap(c01, c45, w[0], w[2]);
  hswap(c23, c67, w[1], w[3]);
  const unsigned d01 = pk_bf16(p[8], p[9]);
  const unsigned d45 = pk_bf16(p[12], p[13]);
  const unsigned d23 = pk_bf16(p[10], p[11]);
  const unsigned d67 = pk_bf16(p[14], p[15]);
  hswap(d01, d45, w[4], w[6]);
  hswap(d23, d67, w[5], w[7]);
  __builtin_memcpy(&f0, &w[0], 16);
  __builtin_memcpy(&f1, &w[4], 16);
}

__global__ __launch_bounds__(64, 4) void flash_attn(
    const bf16_t* __restrict__ Q,   // [B*H, S, 64] (pre-scaled by 0.125*log2e)
    const bf16_t* __restrict__ Kc,  // [B*KV, S, 64]
    const bf16_t* __restrict__ Vt,  // [B*KV, 64, S]
    bf16_t* __restrict__ O) {       // [B, S, H*64]
  // decode: XCD (n&7) owns bh group; rank (j>>3) heavy-first
  const int n = blockIdx.x;
  const int xcd = n & 7;
  const int j = n >> 3;
  const int bh = xcd * 8 + (j & 7);
  const int T = 63 - (j >> 3);          // q-tile index, heavy ranks first
  const int b = bh >> 5, h = bh & 31;
  const int kvh = b * KV_ + (h >> 2);
  const int lane = threadIdx.x & 63;
  const int cq = lane & 31, hh = lane >> 5;
  const int q0 = T * 32, qg = q0 + cq;

  const bf16_t* kb = Kc + (size_t)kvh * S_ * HD_;
  const bf16_t* vb = Vt + (size_t)kvh * HD_ * S_;

  // Q fragments (B operand): lane holds Q[q0+cq][ds*16 + hh*8 .. +8]
  const bf16_t* qp = Q + ((size_t)bh * S_ + qg) * HD_ + hh * 8;
  short8 qf[4];
#pragma unroll
  for (int ds = 0; ds < 4; ds++) qf[ds] = *(const short8*)(qp + ds * 16);

  floatx16 o0 = {}, o1 = {};
  float m = -1e30f, l = 0.f;
  const int nt = T + 1;                 // 32-k tiles (causal)

  // per-lane streaming pointers
  const bf16_t* kp  = kb + (size_t)cq * HD_ + hh * 8;        // += 32*HD_ per tile
  const bf16_t* vp0 = vb + (size_t)cq * S_ + hh * 8;         // d 0..31,  += 32
  const bf16_t* vp1 = vb + (size_t)(32 + cq) * S_ + hh * 8;  // d 32..63, += 32

  for (int kt = 0; kt < nt; kt++) {
    // K fragments (A operand), 4 d-slices
    const short8 kf0 = *(const short8*)(kp);
    const short8 kf1 = *(const short8*)(kp + 16);
    const short8 kf2 = *(const short8*)(kp + 32);
    const short8 kf3 = *(const short8*)(kp + 48);
    // V fragments for this tile -- issued now, consumed after softmax
    const short8 vf00 = *(const short8*)(vp0);
    const short8 vf01 = *(const short8*)(vp0 + 16);
    const short8 vf10 = *(const short8*)(vp1);
    const short8 vf11 = *(const short8*)(vp1 + 16);
    kp += 32 * HD_;
    vp0 += 32; vp1 += 32;

    // QK^T: S^T[k=0..31][q=0..31], K-dim = d = 64 in 4 slices
    floatx16 s = {};
    __builtin_amdgcn_s_setprio(1);
    s = __builtin_amdgcn_mfma_f32_32x32x16_bf16(kf0, qf[0], s, 0, 0, 0);
    s = __builtin_amdgcn_mfma_f32_32x32x16_bf16(kf1, qf[1], s, 0, 0, 0);
    s = __builtin_amdgcn_mfma_f32_32x32x16_bf16(kf2, qf[2], s, 0, 0, 0);
    s = __builtin_amdgcn_mfma_f32_32x32x16_bf16(kf3, qf[3], s, 0, 0, 0);
    __builtin_amdgcn_s_setprio(0);

    // causal mask: diag tile is the last one
    if (kt == T) {
      const int kb0 = kt * 32 + 4 * hh;
#pragma unroll
      for (int r = 0; r < 16; r++) {
        const int kg = kb0 + (r & 3) + 8 * (r >> 2);
        s[r] = (kg <= qg) ? s[r] : -1e30f;
      }
    }

    // row max: lane-local tree over 16 + cross-half merge
    float t[8];
#pragma unroll
    for (int i = 0; i < 8; i++) t[i] = fmaxf(s[i], s[i + 8]);
#pragma unroll
    for (int st = 4; st >= 1; st >>= 1)
#pragma unroll
      for (int i = 0; i < st; i++) t[i] = fmaxf(t[i], t[i + st]);
    const float mx = fmaxf(t[0], __shfl_xor(t[0], 32, 64));

    // defer-max (T13): only rescale when max grew by > 8 (exp2 domain)
    if (!__all(mx <= m + 8.0f)) {
      const float mn = fmaxf(m, mx);
      const float a = fexp2(m - mn);
      l *= a;
#pragma unroll
      for (int i = 0; i < 16; i++) { o0[i] *= a; o1[i] *= a; }
      m = mn;
    }

    // P = exp2(S - m), row-sum (per-half partial, merged at store)
    floatx16 s2 = s;
#pragma unroll
    for (int i = 0; i < 16; i++) s2[i] = fexp2(s2[i] - m);
    float u[8];
#pragma unroll
    for (int i = 0; i < 8; i++) u[i] = s2[i] + s2[i + 8];
#pragma unroll
    for (int st = 4; st >= 1; st >>= 1)
#pragma unroll
      for (int i = 0; i < st; i++) u[i] += u[i + st];
    l += u[0];

    // P -> bf16 B-fragments in-register (8 cvt_pk + 4 half-swaps)
    short8 pf0, pf1;
    build_pfrag(s2, pf0, pf1);

    // PV: O^T[d][q] += V^T x P^T, two d-blocks x two 16-k slices
    __builtin_amdgcn_s_setprio(1);
    o0 = __builtin_amdgcn_mfma_f32_32x32x16_bf16(vf00, pf0, o0, 0, 0, 0);
    o0 = __builtin_amdgcn_mfma_f32_32x32x16_bf16(vf01, pf1, o0, 0, 0, 0);
    o1 = __builtin_amdgcn_mfma_f32_32x32x16_bf16(vf10, pf0, o1, 0, 0, 0);
    o1 = __builtin_amdgcn_mfma_f32_32x32x16_bf16(vf11, pf1, o1, 0, 0, 0);
    __builtin_amdgcn_s_setprio(0);
  }

  // epilogue: merge per-half l, normalize, store
  const float lt = l + __shfl_xor(l, 32, 64);
  const float li = 1.f / lt;
  bf16_t* obp = O + ((size_t)b * S_ + qg) * (H_ * HD_) + h * HD_ + hh * 4;
#pragma unroll
  for (int rq = 0; rq < 4; rq++) {
    uint2 w0;
    w0.x = pk_bf16(o0[4 * rq] * li, o0[4 * rq + 1] * li);
    w0.y = pk_bf16(o0[4 * rq + 2] * li, o0[4 * rq + 3] * li);
    *(uint2*)(obp + rq * 8) = w0;
    uint2 w1;
    w1.x = pk_bf16(o1[4 * rq] * li, o1[4 * rq + 1] * li);
    w1.y = pk_bf16(o1[4 * rq + 2] * li, o1[4 * rq + 3] * li);
    *(uint2*)(obp + 32 + rq * 8) = w1;
  }
}

extern "C" void kernel_launch(void* const* d_in, const int* in_sizes, int n_in,
                              void* d_out, int out_size, void* d_ws, size_t ws_size,
                              hipStream_t stream) {
  const float* x    = (const float*)d_in[0];
  const float* cs   = (const float*)d_in[1];
  const float* sn   = (const float*)d_in[2];
  const float* wqkv = (const float*)d_in[3];
  const float* wout = (const float*)d_in[4];
  float* out = (float*)d_out;

  char* ws = (char*)d_ws;
  bf16_t*  xb    = (bf16_t*)(ws);                 // 16,777,216 B
  bf16_t*  wqkvb = (bf16_t*)(ws + 16777216);      // 12,582,912 B
  bf16_t*  woutb = (bf16_t*)(ws + 29360128);      //  8,388,608 B
  bf16_t*  qb    = (bf16_t*)(ws + 37748736);      // 16,777,216 B
  bf16_t*  kb    = (bf16_t*)(ws + 54525952);      //  4,194,304 B
  bf16_t*  vtb   = (bf16_t*)(ws + 58720256);      //  4,194,304 B
  bf16_t*  attnb = (bf16_t*)(ws + 62914560);      // 16,777,216 B
  unsigned* tab  = (unsigned*)(ws + 79691776);    //    524,288 B (total ~80 MB)

  prep<<<18944, 256, 0, stream>>>(x, xb, wqkv, wqkvb, wout, woutb, cs, sn, tab);
  gemm_qkv<<<dim3(24, 32), 256, 0, stream>>>(xb, wqkvb, tab, qb, kb, vtb);
  flash_attn<<<4096, 64, 0, stream>>>(qb, kb, vtb, attnb);
  gemm_bt<<<dim3(16, 32), 256, 0, stream>>>(attnb, woutb, out, 4096, 2048, 2048);
}

// Round 5
// 354.408 us; speedup vs baseline: 1.0103x; 1.0103x over previous
//
#include <hip/hip_runtime.h>
#include <hip/hip_fp16.h>

#define B_ 2
#define S_ 2048
#define D_ 2048
#define H_ 32
#define KV_ 8
#define HD_ 64

typedef unsigned short bf16_t;
typedef __attribute__((ext_vector_type(8))) short short8;
typedef __attribute__((ext_vector_type(4))) float floatx4;
typedef __attribute__((ext_vector_type(16))) float floatx16;

__device__ __forceinline__ bf16_t f2bf(float f) {
  union { float f; unsigned u; } c; c.f = f;
  unsigned u = c.u;
  u += 0x7fffu + ((u >> 16) & 1u);          // round-to-nearest-even
  return (bf16_t)(u >> 16);
}

__device__ __forceinline__ unsigned pk_bf16(float a, float b) {
#if __has_builtin(__builtin_amdgcn_cvt_pk_bf16_f32)
  auto v = __builtin_amdgcn_cvt_pk_bf16_f32(a, b);
  unsigned u; __builtin_memcpy(&u, &v, 4); return u;
#else
  return (unsigned)f2bf(a) | ((unsigned)f2bf(b) << 16);
#endif
}

__device__ __forceinline__ float fexp2(float x) {
#if __has_builtin(__builtin_amdgcn_exp2f)
  return __builtin_amdgcn_exp2f(x);
#else
  return exp2f(x);
#endif
}

__device__ __forceinline__ void load_lds16(const void* g, void* l) {
  __builtin_amdgcn_global_load_lds(
      (const __attribute__((address_space(1))) void*)g,
      (__attribute__((address_space(3))) void*)l, 16, 0, 0);
}

// ---------------- prep: fp32->bf16 casts + packed fp16 rope table ----------------
__device__ __forceinline__ void cvt4(const float* __restrict__ in,
                                     bf16_t* __restrict__ out, int i) {
  float4 v = ((const float4*)in)[i];
  ushort4 o;
  o.x = f2bf(v.x); o.y = f2bf(v.y); o.z = f2bf(v.z); o.w = f2bf(v.w);
  ((ushort4*)out)[i] = o;
}

__global__ __launch_bounds__(256) void prep(
    const float* __restrict__ x, bf16_t* __restrict__ xb,
    const float* __restrict__ wqkv, bf16_t* __restrict__ wqkvb,
    const float* __restrict__ wout, bf16_t* __restrict__ woutb,
    const float* __restrict__ cs, const float* __restrict__ sn,
    unsigned* __restrict__ tab) {
  const int bid = blockIdx.x;
  if (bid < 8192) {
    cvt4(x, xb, bid * 256 + threadIdx.x);
  } else if (bid < 14336) {
    cvt4(wqkv, wqkvb, (bid - 8192) * 256 + threadIdx.x);
  } else if (bid < 18432) {
    cvt4(wout, woutb, (bid - 14336) * 256 + threadIdx.x);
  } else {
    const int i = (bid - 18432) * 256 + threadIdx.x;   // 131072 entries
    __half2 h = __floats2half2_rn(cs[i], sn[i]);
    unsigned u; __builtin_memcpy(&u, &h, 4);
    tab[i] = u;
  }
}

// ---------------- bf16 GEMM: C[M,N] = A[M,K] * B^T (f32 out) ----------------
__global__ __launch_bounds__(256) void gemm_bt(
    const bf16_t* __restrict__ A, const bf16_t* __restrict__ Bm,
    float* __restrict__ C, int M, int N, int K) {
  __shared__ __attribute__((aligned(16))) bf16_t As[128 * 32];
  __shared__ __attribute__((aligned(16))) bf16_t Bs[128 * 32];
  const int tid = threadIdx.x;
  const int lane = tid & 63;
  const int wave = tid >> 6;
  const int bm = blockIdx.y * 128, bn = blockIdx.x * 128;
  const int wm = (wave >> 1) * 64, wn = (wave & 1) * 64;
  const int lr = lane & 15, quad = lane >> 4;

  floatx4 acc[4][4] = {};

  const int t0 = tid, t1 = tid + 256;
  const int r0 = t0 >> 2, c0 = (t0 & 3) * 8;
  const int r1 = t1 >> 2, c1 = (t1 & 3) * 8;

  const bf16_t* Ab = A + (size_t)bm * K;
  const bf16_t* Bb = Bm + (size_t)bn * K;

  for (int k0 = 0; k0 < K; k0 += 32) {
    __syncthreads();
    load_lds16(Ab + (size_t)r0 * K + k0 + c0, &As[t0 * 8]);
    load_lds16(Ab + (size_t)r1 * K + k0 + c1, &As[t1 * 8]);
    load_lds16(Bb + (size_t)r0 * K + k0 + c0, &Bs[t0 * 8]);
    load_lds16(Bb + (size_t)r1 * K + k0 + c1, &Bs[t1 * 8]);
    __syncthreads();

    short8 af[4], bfr[4];
#pragma unroll
    for (int i = 0; i < 4; i++) {
      af[i]  = *(const short8*)&As[(wm + i * 16 + lr) * 32 + quad * 8];
      bfr[i] = *(const short8*)&Bs[(wn + i * 16 + lr) * 32 + quad * 8];
    }
#pragma unroll
    for (int mi = 0; mi < 4; mi++)
#pragma unroll
      for (int ni = 0; ni < 4; ni++)
        acc[mi][ni] = __builtin_amdgcn_mfma_f32_16x16x32_bf16(af[mi], bfr[ni], acc[mi][ni], 0, 0, 0);
  }

#pragma unroll
  for (int mi = 0; mi < 4; mi++) {
    const int row = bm + wm + mi * 16 + quad * 4;
#pragma unroll
    for (int ni = 0; ni < 4; ni++) {
      const int col = bn + wn + ni * 16 + lr;
      float* cp = C + (size_t)row * N + col;
#pragma unroll
      for (int r = 0; r < 4; r++) cp[(size_t)r * N] = acc[mi][ni][r];
    }
  }
}

// ---------------- fused QKV GEMM + RoPE (fp16 table) + repack ----------------
__global__ __launch_bounds__(256, 4) void gemm_qkv(
    const bf16_t* __restrict__ A, const bf16_t* __restrict__ Bm,
    const unsigned* __restrict__ tab,
    bf16_t* __restrict__ q, bf16_t* __restrict__ k, bf16_t* __restrict__ vt) {
  const int K = 2048;
  __shared__ __attribute__((aligned(16))) bf16_t As[128 * 32];
  __shared__ __attribute__((aligned(16))) bf16_t Bs[128 * 32];
  __shared__ __attribute__((aligned(16))) bf16_t Ts[4][32 * 72];  // V transpose (2-pass)
  const int tid = threadIdx.x;
  const int lane = tid & 63;
  const int wave = tid >> 6;
  const int bm = blockIdx.y * 128, bn = blockIdx.x * 128;
  const int wm = (wave >> 1) * 64, wn = (wave & 1) * 64;
  const int lr = lane & 15, quad = lane >> 4;

  floatx4 acc[4][4] = {};

  const int t0 = tid, t1 = tid + 256;
  const int r0 = t0 >> 2, c0 = (t0 & 3) * 8;
  const int r1 = t1 >> 2, c1 = (t1 & 3) * 8;

  const bf16_t* Ab = A + (size_t)bm * K;
  const bf16_t* Bb = Bm + (size_t)bn * K;

  for (int k0 = 0; k0 < K; k0 += 32) {
    __syncthreads();
    load_lds16(Ab + (size_t)r0 * K + k0 + c0, &As[t0 * 8]);
    load_lds16(Ab + (size_t)r1 * K + k0 + c1, &As[t1 * 8]);
    load_lds16(Bb + (size_t)r0 * K + k0 + c0, &Bs[t0 * 8]);
    load_lds16(Bb + (size_t)r1 * K + k0 + c1, &Bs[t1 * 8]);
    __syncthreads();

    short8 af[4], bfr[4];
#pragma unroll
    for (int i = 0; i < 4; i++) {
      af[i]  = *(const short8*)&As[(wm + i * 16 + lr) * 32 + quad * 8];
      bfr[i] = *(const short8*)&Bs[(wn + i * 16 + lr) * 32 + quad * 8];
    }
#pragma unroll
    for (int mi = 0; mi < 4; mi++)
#pragma unroll
      for (int ni = 0; ni < 4; ni++)
        acc[mi][ni] = __builtin_amdgcn_mfma_f32_16x16x32_bf16(af[mi], bfr[ni], acc[mi][ni], 0, 0, 0);
  }

  const int f0 = bn + wn;              // wave-uniform feature base (multiple of 64)
  const int srow0 = bm + wm;
  const int bb = srow0 >> 11, s0 = srow0 & 2047;

  if (f0 < 2560) {                     // Q or K head: in-register rope
    const bool isq = (f0 < 2048);
    const float scale = isq ? 0.18033688011f : 1.0f;   // 0.125 * log2(e)
    bf16_t* dst = isq ? (q + (size_t)(bb * H_ + (f0 >> 6)) * S_ * HD_)
                      : (k + (size_t)(bb * KV_ + ((f0 - 2048) >> 6)) * S_ * HD_);
#pragma unroll
    for (int mi = 0; mi < 4; mi++) {
#pragma unroll
      for (int r = 0; r < 4; r++) {
        const int sr = s0 + mi * 16 + quad * 4 + r;
        const unsigned* tp = tab + (size_t)sr * HD_;
        bf16_t* drow = dst + (size_t)sr * HD_;
#pragma unroll
        for (int ni = 0; ni < 4; ni++) {
          const int d = ni * 16 + lr;
          const unsigned w = tp[d];
          __half2 h2; __builtin_memcpy(&h2, &w, 4);
          const float2 cf = __half22float2(h2);
          const float t = acc[mi][ni][r];
          const float oth = acc[mi][ni ^ 2][r];
          const float rot = (ni < 2) ? -oth : oth;   // d<32 iff ni<2
          drow[d] = f2bf((t * cf.x + rot * cf.y) * scale);
        }
      }
    }
  } else {                             // V head: 2-pass transpose via 9 KB/wave LDS
    const int hv = (f0 - 2560) >> 6;
    bf16_t* ts = Ts[wave];
    const int rl = lane >> 1, hf = lane & 1;
#pragma unroll
    for (int p = 0; p < 2; p++) {
#pragma unroll
      for (int nn = 0; nn < 2; nn++) {
        const int ni = 2 * p + nn;
#pragma unroll
        for (int mi = 0; mi < 4; mi++) {
          uint2 pw;
          pw.x = pk_bf16(acc[mi][ni][0], acc[mi][ni][1]);
          pw.y = pk_bf16(acc[mi][ni][2], acc[mi][ni][3]);
          *(uint2*)&ts[(nn * 16 + lr) * 72 + mi * 16 + quad * 4] = pw;
        }
      }
      // same-wave RAW/WAR: DS pipe is in-order per wave, compiler emits lgkmcnt
      bf16_t* vrow = vt + ((size_t)(bb * KV_ + hv) * HD_ + p * 32 + rl) * S_ + s0 + hf * 32;
#pragma unroll
      for (int j = 0; j < 4; j++)
        *(short8*)(vrow + j * 8) = *(const short8*)&ts[rl * 72 + hf * 32 + j * 8];
    }
  }
}

// ---------------- flash attention v6: barrier-free + register ping-pong prefetch ----
// One 32-q-row tile per independent 64-thread block (no LDS, no barriers).
// K/V fragments for tile t+2 are ISSUED right after tile t's set is consumed
// (K after QK^T, V after PV) -> ~1 full tile of compute between issue and use,
// hiding L2/L3/HBM latency; the compiler emits minimal counted vmcnt for these
// tracked register loads. LPT: heavy q-tiles (large T) dispatch first.
// XCD swizzle: XCD x owns heads [8x, 8x+8) => 4 kv-heads = 2 MB < 4 MB L2/XCD.

// halves-exchange: x = [a.lo | b.lo], y = [a.hi | b.hi] (lanes 0-31 | 32-63)
__device__ __forceinline__ void hswap(unsigned a, unsigned b, unsigned& x, unsigned& y) {
#if __has_builtin(__builtin_amdgcn_permlane32_swap)
  auto r = __builtin_amdgcn_permlane32_swap(a, b, false, false);
  x = (unsigned)r[0]; y = (unsigned)r[1];
#else
  const unsigned pa = (unsigned)__shfl_xor((int)a, 32, 64);
  const unsigned pb = (unsigned)__shfl_xor((int)b, 32, 64);
  const bool hi = (threadIdx.x & 32) != 0;
  x = hi ? pb : a;
  y = hi ? b : pa;
#endif
}

// one 32-k tile of P in lane regs -> two PV B-fragments (k-slices of 16)
__device__ __forceinline__ void build_pfrag(const floatx16& p, short8& f0, short8& f1) {
  unsigned w[8];
  const unsigned c01 = pk_bf16(p[0], p[1]);
  const unsigned c45 = pk_bf16(p[4], p[5]);
  const unsigned c23 = pk_bf16(p[2], p[3]);
  const unsigned c67 = pk_bf16(p[6], p[7]);
  hswap(c01, c45, w[0], w[2]);
  hswap(c23, c67, w[1], w[3]);
  const unsigned d01 = pk_bf16(p[8], p[9]);
  const unsigned d45 = pk_bf16(p[12], p[13]);
  const unsigned d23 = pk_bf16(p[10], p[11]);
  const unsigned d67 = pk_bf16(p[14], p[15]);
  hswap(d01, d45, w[4], w[6]);
  hswap(d23, d67, w[5], w[7]);
  __builtin_memcpy(&f0, &w[0], 16);
  __builtin_memcpy(&f1, &w[4], 16);
}

__global__ __launch_bounds__(64) void flash_attn(
    const bf16_t* __restrict__ Q,   // [B*H, S, 64] (pre-scaled by 0.125*log2e)
    const bf16_t* __restrict__ Kc,  // [B*KV, S, 64]
    const bf16_t* __restrict__ Vt,  // [B*KV, 64, S]
    bf16_t* __restrict__ O) {       // [B, S, H*64]
  // bid bits: [T'(6)][c(3)][x(3)] -> head = x*8 + c (XCD-local), T = 63 - T' (LPT)
  const int bid = blockIdx.x;
  const int head = ((bid & 7) << 3) | ((bid >> 3) & 7);
  const int T = 63 - (bid >> 6);
  const int b = head >> 5, h = head & 31;
  const int kvh = b * KV_ + (h >> 2);
  const int lane = threadIdx.x & 63;
  const int cq = lane & 31, hh = lane >> 5;
  const int q0 = T * 32, qg = q0 + cq;
  const int nt = T + 1;                 // 32-k tiles (causal)

  const bf16_t* kb = Kc + (size_t)kvh * S_ * HD_;
  const bf16_t* vb = Vt + (size_t)kvh * HD_ * S_;

  // Q fragments (B operand): lane holds Q[q0+cq][ds*16 + hh*8 .. +8]
  const bf16_t* qp = Q + ((size_t)head * S_ + qg) * HD_ + hh * 8;
  short8 qf[4];
#pragma unroll
  for (int ds = 0; ds < 4; ds++) qf[ds] = *(const short8*)(qp + ds * 16);

  // per-lane streaming base pointers
  const bf16_t* kp  = kb + (size_t)cq * HD_ + hh * 8;        // + t*32*HD_
  const bf16_t* vp0 = vb + (size_t)cq * S_ + hh * 8;         // d 0..31,  + t*32
  const bf16_t* vp1 = vb + (size_t)(32 + cq) * S_ + hh * 8;  // d 32..63, + t*32

  floatx16 o0 = {}, o1 = {};
  float m = -1e30f, l = 0.f;

  short8 kA[4], vA[4], kB[4], vB[4];    // ping-pong prefetch sets (const-indexed only)

#define LDK(dst, t) { const bf16_t* _p = kp + (size_t)(t) * (32 * HD_);              \
    dst[0] = *(const short8*)_p;        dst[1] = *(const short8*)(_p + 16);          \
    dst[2] = *(const short8*)(_p + 32); dst[3] = *(const short8*)(_p + 48); }
#define LDV(dst, t) { const bf16_t* _p0 = vp0 + (t) * 32; const bf16_t* _p1 = vp1 + (t) * 32; \
    dst[0] = *(const short8*)_p0; dst[1] = *(const short8*)(_p0 + 16);               \
    dst[2] = *(const short8*)_p1; dst[3] = *(const short8*)(_p1 + 16); }

  auto STEP = [&](short8 (&ks)[4], short8 (&vs)[4], int t) {
    // QK^T: S^T[k=0..31][q=0..31], K-dim = d = 64 in 4 slices
    floatx16 s = {};
    __builtin_amdgcn_s_setprio(1);
#pragma unroll
    for (int ds = 0; ds < 4; ds++)
      s = __builtin_amdgcn_mfma_f32_32x32x16_bf16(ks[ds], qf[ds], s, 0, 0, 0);
    __builtin_amdgcn_s_setprio(0);
    if (t + 2 < nt) LDK(ks, t + 2);     // reissue K set -> lands during next tile

    if (t == nt - 1) {                  // causal mask on the diag tile
      const int kb0 = t * 32 + 4 * hh;
#pragma unroll
      for (int r = 0; r < 16; r++) {
        const int kg = kb0 + (r & 3) + 8 * (r >> 2);
        s[r] = (kg <= qg) ? s[r] : -1e30f;
      }
    }

    // row max: lane-local tree over 16 + cross-half merge
    float tt[8];
#pragma unroll
    for (int i = 0; i < 8; i++) tt[i] = fmaxf(s[i], s[i + 8]);
#pragma unroll
    for (int st = 4; st >= 1; st >>= 1)
#pragma unroll
      for (int i = 0; i < st; i++) tt[i] = fmaxf(tt[i], tt[i + st]);
    const float mx = fmaxf(tt[0], __shfl_xor(tt[0], 32, 64));

    // defer-max (T13): only rescale when max grew by > 8 (exp2 domain)
    if (!__all(mx <= m + 8.0f)) {
      const float mn = fmaxf(m, mx);
      const float a = fexp2(m - mn);
      l *= a;
#pragma unroll
      for (int i = 0; i < 16; i++) { o0[i] *= a; o1[i] *= a; }
      m = mn;
    }

    // P = exp2(S - m), row-sum (per-half partial, merged at store)
#pragma unroll
    for (int i = 0; i < 16; i++) s[i] = fexp2(s[i] - m);
    float u[8];
#pragma unroll
    for (int i = 0; i < 8; i++) u[i] = s[i] + s[i + 8];
#pragma unroll
    for (int st = 4; st >= 1; st >>= 1)
#pragma unroll
      for (int i = 0; i < st; i++) u[i] += u[i + st];
    l += u[0];

    // P -> bf16 B-fragments in-register (8 cvt_pk + 4 half-swaps)
    short8 pf0, pf1;
    build_pfrag(s, pf0, pf1);

    // PV: O^T[d][q] += V^T x P^T, two d-blocks x two 16-k slices
    __builtin_amdgcn_s_setprio(1);
    o0 = __builtin_amdgcn_mfma_f32_32x32x16_bf16(vs[0], pf0, o0, 0, 0, 0);
    o0 = __builtin_amdgcn_mfma_f32_32x32x16_bf16(vs[1], pf1, o0, 0, 0, 0);
    o1 = __builtin_amdgcn_mfma_f32_32x32x16_bf16(vs[2], pf0, o1, 0, 0, 0);
    o1 = __builtin_amdgcn_mfma_f32_32x32x16_bf16(vs[3], pf1, o1, 0, 0, 0);
    __builtin_amdgcn_s_setprio(0);
    if (t + 2 < nt) LDV(vs, t + 2);     // reissue V set -> lands during next tile
  };

  LDK(kA, 0); LDV(vA, 0);
  if (nt > 1) { LDK(kB, 1); LDV(vB, 1); }

  for (int kt = 0; kt < nt; kt += 2) {
    STEP(kA, vA, kt);
    if (kt + 1 >= nt) break;
    STEP(kB, vB, kt + 1);
  }
#undef LDK
#undef LDV

  // epilogue: merge per-half l, normalize, store
  const float lt = l + __shfl_xor(l, 32, 64);
  const float li = 1.f / lt;
  bf16_t* obp = O + ((size_t)b * S_ + qg) * (H_ * HD_) + h * HD_ + hh * 4;
#pragma unroll
  for (int rq = 0; rq < 4; rq++) {
    uint2 w0;
    w0.x = pk_bf16(o0[4 * rq] * li, o0[4 * rq + 1] * li);
    w0.y = pk_bf16(o0[4 * rq + 2] * li, o0[4 * rq + 3] * li);
    *(uint2*)(obp + rq * 8) = w0;
    uint2 w1;
    w1.x = pk_bf16(o1[4 * rq] * li, o1[4 * rq + 1] * li);
    w1.y = pk_bf16(o1[4 * rq + 2] * li, o1[4 * rq + 3] * li);
    *(uint2*)(obp + 32 + rq * 8) = w1;
  }
}

extern "C" void kernel_launch(void* const* d_in, const int* in_sizes, int n_in,
                              void* d_out, int out_size, void* d_ws, size_t ws_size,
                              hipStream_t stream) {
  const float* x    = (const float*)d_in[0];
  const float* cs   = (const float*)d_in[1];
  const float* sn   = (const float*)d_in[2];
  const float* wqkv = (const float*)d_in[3];
  const float* wout = (const float*)d_in[4];
  float* out = (float*)d_out;

  char* ws = (char*)d_ws;
  bf16_t*  xb    = (bf16_t*)(ws);                 // 16,777,216 B
  bf16_t*  wqkvb = (bf16_t*)(ws + 16777216);      // 12,582,912 B
  bf16_t*  woutb = (bf16_t*)(ws + 29360128);      //  8,388,608 B
  bf16_t*  qb    = (bf16_t*)(ws + 37748736);      // 16,777,216 B
  bf16_t*  kb    = (bf16_t*)(ws + 54525952);      //  4,194,304 B
  bf16_t*  vtb   = (bf16_t*)(ws + 58720256);      //  4,194,304 B
  bf16_t*  attnb = (bf16_t*)(ws + 62914560);      // 16,777,216 B
  unsigned* tab  = (unsigned*)(ws + 79691776);    //    524,288 B (total ~80 MB)

  prep<<<18944, 256, 0, stream>>>(x, xb, wqkv, wqkvb, wout, woutb, cs, sn, tab);
  gemm_qkv<<<dim3(24, 32), 256, 0, stream>>>(xb, wqkvb, tab, qb, kb, vtb);
  flash_attn<<<4096, 64, 0, stream>>>(qb, kb, vtb, attnb);
  gemm_bt<<<dim3(16, 32), 256, 0, stream>>>(attnb, woutb, out, 4096, 2048, 2048);
}

// Round 6
// 292.118 us; speedup vs baseline: 1.2258x; 1.2132x over previous
//
#include <hip/hip_runtime.h>
#include <hip/hip_fp16.h>

#define B_ 2
#define S_ 2048
#define D_ 2048
#define H_ 32
#define KV_ 8
#define HD_ 64

typedef unsigned short bf16_t;
typedef __attribute__((ext_vector_type(8))) short short8;
typedef __attribute__((ext_vector_type(4))) float floatx4;
typedef __attribute__((ext_vector_type(16))) float floatx16;

__device__ __forceinline__ bf16_t f2bf(float f) {
  union { float f; unsigned u; } c; c.f = f;
  unsigned u = c.u;
  u += 0x7fffu + ((u >> 16) & 1u);          // round-to-nearest-even
  return (bf16_t)(u >> 16);
}

__device__ __forceinline__ unsigned pk_bf16(float a, float b) {
#if __has_builtin(__builtin_amdgcn_cvt_pk_bf16_f32)
  auto v = __builtin_amdgcn_cvt_pk_bf16_f32(a, b);
  unsigned u; __builtin_memcpy(&u, &v, 4); return u;
#else
  return (unsigned)f2bf(a) | ((unsigned)f2bf(b) << 16);
#endif
}

__device__ __forceinline__ float fexp2(float x) {
#if __has_builtin(__builtin_amdgcn_exp2f)
  return __builtin_amdgcn_exp2f(x);
#else
  return exp2f(x);
#endif
}

__device__ __forceinline__ void load_lds16(const void* g, void* l) {
  __builtin_amdgcn_global_load_lds(
      (const __attribute__((address_space(1))) void*)g,
      (__attribute__((address_space(3))) void*)l, 16, 0, 0);
}

// ---------------- prep: fp32->bf16 casts + packed fp16 rope table ----------------
__device__ __forceinline__ void cvt4(const float* __restrict__ in,
                                     bf16_t* __restrict__ out, int i) {
  float4 v = ((const float4*)in)[i];
  ushort4 o;
  o.x = f2bf(v.x); o.y = f2bf(v.y); o.z = f2bf(v.z); o.w = f2bf(v.w);
  ((ushort4*)out)[i] = o;
}

__global__ __launch_bounds__(256) void prep(
    const float* __restrict__ x, bf16_t* __restrict__ xb,
    const float* __restrict__ wqkv, bf16_t* __restrict__ wqkvb,
    const float* __restrict__ wout, bf16_t* __restrict__ woutb,
    const float* __restrict__ cs, const float* __restrict__ sn,
    unsigned* __restrict__ tab) {
  const int bid = blockIdx.x;
  if (bid < 8192) {
    cvt4(x, xb, bid * 256 + threadIdx.x);
  } else if (bid < 14336) {
    cvt4(wqkv, wqkvb, (bid - 8192) * 256 + threadIdx.x);
  } else if (bid < 18432) {
    cvt4(wout, woutb, (bid - 14336) * 256 + threadIdx.x);
  } else {
    const int i = (bid - 18432) * 256 + threadIdx.x;   // 131072 entries
    __half2 h = __floats2half2_rn(cs[i], sn[i]);
    unsigned u; __builtin_memcpy(&u, &h, 4);
    tab[i] = u;
  }
}

// ---------------- bf16 GEMM: C[M,N] = A[M,K] * B^T (f32 out) ----------------
// BK=64 (half the barrier drains of BK=32), XOR-swizzled LDS:
// LDS[row][slot] = global[row][slot ^ (row&7)] (slot = 16B chunk, 8/row).
__global__ __launch_bounds__(256) void gemm_bt(
    const bf16_t* __restrict__ A, const bf16_t* __restrict__ Bm,
    float* __restrict__ C, int M, int N, int K) {
  __shared__ __attribute__((aligned(16))) bf16_t As[128 * 64];  // 16 KB
  __shared__ __attribute__((aligned(16))) bf16_t Bs[128 * 64];  // 16 KB
  const int tid = threadIdx.x;
  const int lane = tid & 63;
  const int wave = tid >> 6;
  const int bm = blockIdx.y * 128, bn = blockIdx.x * 128;
  const int wm = (wave >> 1) * 64, wn = (wave & 1) * 64;
  const int lr = lane & 15, quad = lane >> 4;

  floatx4 acc[4][4] = {};

  const bf16_t* Ab = A + (size_t)bm * K;
  const bf16_t* Bb = Bm + (size_t)bn * K;

  for (int k0 = 0; k0 < K; k0 += 64) {
    __syncthreads();
#pragma unroll
    for (int p = 0; p < 4; p++) {
      const int idx = p * 256 + tid;
      const int row = idx >> 3, sc = idx & 7;
      const int gc = sc ^ (row & 7);
      load_lds16(Ab + (size_t)row * K + k0 + gc * 8, &As[idx * 8]);
      load_lds16(Bb + (size_t)row * K + k0 + gc * 8, &Bs[idx * 8]);
    }
    __syncthreads();

#pragma unroll
    for (int ks = 0; ks < 2; ks++) {
      short8 af[4], bfr[4];
#pragma unroll
      for (int i = 0; i < 4; i++) {
        const int ra = wm + i * 16 + lr;
        const int rb = wn + i * 16 + lr;
        af[i]  = *(const short8*)&As[ra * 64 + (((ks * 4 + quad) ^ (ra & 7)) * 8)];
        bfr[i] = *(const short8*)&Bs[rb * 64 + (((ks * 4 + quad) ^ (rb & 7)) * 8)];
      }
#pragma unroll
      for (int mi = 0; mi < 4; mi++)
#pragma unroll
        for (int ni = 0; ni < 4; ni++)
          acc[mi][ni] = __builtin_amdgcn_mfma_f32_16x16x32_bf16(af[mi], bfr[ni], acc[mi][ni], 0, 0, 0);
    }
  }

#pragma unroll
  for (int mi = 0; mi < 4; mi++) {
    const int row = bm + wm + mi * 16 + quad * 4;
#pragma unroll
    for (int ni = 0; ni < 4; ni++) {
      const int col = bn + wn + ni * 16 + lr;
      float* cp = C + (size_t)row * N + col;
#pragma unroll
      for (int r = 0; r < 4; r++) cp[(size_t)r * N] = acc[mi][ni][r];
    }
  }
}

// ---------------- fused QKV GEMM + RoPE (fp16 table) + repack ----------------
__global__ __launch_bounds__(256, 4) void gemm_qkv(
    const bf16_t* __restrict__ A, const bf16_t* __restrict__ Bm,
    const unsigned* __restrict__ tab,
    bf16_t* __restrict__ q, bf16_t* __restrict__ k, bf16_t* __restrict__ vt) {
  const int K = 2048;
  __shared__ __attribute__((aligned(16))) bf16_t As[128 * 64];  // 16 KB
  __shared__ __attribute__((aligned(16))) bf16_t Bs[128 * 64];  // 16 KB
  __shared__ __attribute__((aligned(16))) bf16_t Ts[4][32 * 72];  // V transpose (2-pass)
  const int tid = threadIdx.x;
  const int lane = tid & 63;
  const int wave = tid >> 6;
  const int bm = blockIdx.y * 128, bn = blockIdx.x * 128;
  const int wm = (wave >> 1) * 64, wn = (wave & 1) * 64;
  const int lr = lane & 15, quad = lane >> 4;

  floatx4 acc[4][4] = {};

  const bf16_t* Ab = A + (size_t)bm * K;
  const bf16_t* Bb = Bm + (size_t)bn * K;

  for (int k0 = 0; k0 < K; k0 += 64) {
    __syncthreads();
#pragma unroll
    for (int p = 0; p < 4; p++) {
      const int idx = p * 256 + tid;
      const int row = idx >> 3, sc = idx & 7;
      const int gc = sc ^ (row & 7);
      load_lds16(Ab + (size_t)row * K + k0 + gc * 8, &As[idx * 8]);
      load_lds16(Bb + (size_t)row * K + k0 + gc * 8, &Bs[idx * 8]);
    }
    __syncthreads();

#pragma unroll
    for (int ks = 0; ks < 2; ks++) {
      short8 af[4], bfr[4];
#pragma unroll
      for (int i = 0; i < 4; i++) {
        const int ra = wm + i * 16 + lr;
        const int rb = wn + i * 16 + lr;
        af[i]  = *(const short8*)&As[ra * 64 + (((ks * 4 + quad) ^ (ra & 7)) * 8)];
        bfr[i] = *(const short8*)&Bs[rb * 64 + (((ks * 4 + quad) ^ (rb & 7)) * 8)];
      }
#pragma unroll
      for (int mi = 0; mi < 4; mi++)
#pragma unroll
        for (int ni = 0; ni < 4; ni++)
          acc[mi][ni] = __builtin_amdgcn_mfma_f32_16x16x32_bf16(af[mi], bfr[ni], acc[mi][ni], 0, 0, 0);
    }
  }

  const int f0 = bn + wn;              // wave-uniform feature base (multiple of 64)
  const int srow0 = bm + wm;
  const int bb = srow0 >> 11, s0 = srow0 & 2047;

  if (f0 < 2560) {                     // Q or K head: in-register rope
    const bool isq = (f0 < 2048);
    const float scale = isq ? 0.18033688011f : 1.0f;   // 0.125 * log2(e)
    bf16_t* dst = isq ? (q + (size_t)(bb * H_ + (f0 >> 6)) * S_ * HD_)
                      : (k + (size_t)(bb * KV_ + ((f0 - 2048) >> 6)) * S_ * HD_);
#pragma unroll
    for (int mi = 0; mi < 4; mi++) {
#pragma unroll
      for (int r = 0; r < 4; r++) {
        const int sr = s0 + mi * 16 + quad * 4 + r;
        const unsigned* tp = tab + (size_t)sr * HD_;
        bf16_t* drow = dst + (size_t)sr * HD_;
#pragma unroll
        for (int ni = 0; ni < 4; ni++) {
          const int d = ni * 16 + lr;
          const unsigned w = tp[d];
          __half2 h2; __builtin_memcpy(&h2, &w, 4);
          const float2 cf = __half22float2(h2);
          const float t = acc[mi][ni][r];
          const float oth = acc[mi][ni ^ 2][r];
          const float rot = (ni < 2) ? -oth : oth;   // d<32 iff ni<2
          drow[d] = f2bf((t * cf.x + rot * cf.y) * scale);
        }
      }
    }
  } else {                             // V head: 2-pass transpose via 9 KB/wave LDS
    const int hv = (f0 - 2560) >> 6;
    bf16_t* ts = Ts[wave];
    const int rl = lane >> 1, hf = lane & 1;
#pragma unroll
    for (int p = 0; p < 2; p++) {
#pragma unroll
      for (int nn = 0; nn < 2; nn++) {
        const int ni = 2 * p + nn;
#pragma unroll
        for (int mi = 0; mi < 4; mi++) {
          uint2 pw;
          pw.x = pk_bf16(acc[mi][ni][0], acc[mi][ni][1]);
          pw.y = pk_bf16(acc[mi][ni][2], acc[mi][ni][3]);
          *(uint2*)&ts[(nn * 16 + lr) * 72 + mi * 16 + quad * 4] = pw;
        }
      }
      // same-wave RAW/WAR: DS pipe is in-order per wave, compiler emits lgkmcnt
      bf16_t* vrow = vt + ((size_t)(bb * KV_ + hv) * HD_ + p * 32 + rl) * S_ + s0 + hf * 32;
#pragma unroll
      for (int j = 0; j < 4; j++)
        *(short8*)(vrow + j * 8) = *(const short8*)&ts[rl * 72 + hf * 32 + j * 8];
    }
  }
}

// ---------------- flash attention v7: staged, 4-wave blocks, KVBLK=64 ----------------
// Block owns 128 q-rows (4 waves x 32); K/V staged cooperatively into 32 KB LDS,
// double-buffered, same swizzle convention as v3 (LDS[r][sc]=g[r][sc^(r&7)]).
// Grid 1024 blocks x 4 waves = 4096 waves = 4/SIMD (2x v3's TLP, exact 4 blk/CU).
// LPT: heavy q-blocks (large Tb) first; XCD head-grouping for KV L2 locality.
// Per-wave compute is round-2 v3's verified body (in-reg softmax, cvt_pk+permlane P).

__device__ __forceinline__ void stage64_4w(const bf16_t* __restrict__ gk,
                                           const bf16_t* __restrict__ gv,
                                           bf16_t* kbuf, bf16_t* vbuf, int tid) {
#pragma unroll
  for (int j = 0; j < 2; j++) {
    const int idx = j * 256 + tid;      // 512 chunks of 16B per 64x64 tile
    const int row = idx >> 3;
    const int sc  = idx & 7;
    const int gc  = sc ^ (row & 7);
    load_lds16(gk + (size_t)row * HD_ + gc * 8, kbuf + idx * 8);
    load_lds16(gv + (size_t)row * S_  + gc * 8, vbuf + idx * 8);
  }
}

// halves-exchange: x = [a.lo | b.lo], y = [a.hi | b.hi] (lanes 0-31 | 32-63)
__device__ __forceinline__ void hswap(unsigned a, unsigned b, unsigned& x, unsigned& y) {
#if __has_builtin(__builtin_amdgcn_permlane32_swap)
  auto r = __builtin_amdgcn_permlane32_swap(a, b, false, false);
  x = (unsigned)r[0]; y = (unsigned)r[1];
#else
  const unsigned pa = (unsigned)__shfl_xor((int)a, 32, 64);
  const unsigned pb = (unsigned)__shfl_xor((int)b, 32, 64);
  const bool hi = (threadIdx.x & 32) != 0;
  x = hi ? pb : a;
  y = hi ? b : pa;
#endif
}

// one k-subtile (32 k) of P in lane regs -> two PV B-fragments (k-slices of 16)
__device__ __forceinline__ void build_pfrag(const floatx16& p, short8& f0, short8& f1) {
  unsigned w[8];
  const unsigned c01 = pk_bf16(p[0], p[1]);
  const unsigned c45 = pk_bf16(p[4], p[5]);
  const unsigned c23 = pk_bf16(p[2], p[3]);
  const unsigned c67 = pk_bf16(p[6], p[7]);
  hswap(c01, c45, w[0], w[2]);
  hswap(c23, c67, w[1], w[3]);
  const unsigned d01 = pk_bf16(p[8], p[9]);
  const unsigned d45 = pk_bf16(p[12], p[13]);
  const unsigned d23 = pk_bf16(p[10], p[11]);
  const unsigned d67 = pk_bf16(p[14], p[15]);
  hswap(d01, d45, w[4], w[6]);
  hswap(d23, d67, w[5], w[7]);
  __builtin_memcpy(&f0, &w[0], 16);
  __builtin_memcpy(&f1, &w[4], 16);
}

__global__ __launch_bounds__(256, 2) void flash_attn(
    const bf16_t* __restrict__ Q,   // [B*H, S, 64] (pre-scaled by 0.125*log2e)
    const bf16_t* __restrict__ Kc,  // [B*KV, S, 64]
    const bf16_t* __restrict__ Vt,  // [B*KV, 64, S]
    bf16_t* __restrict__ O) {       // [B, S, H*64]
  __shared__ __attribute__((aligned(16))) bf16_t Ks[2 * 4096];  // 16 KB
  __shared__ __attribute__((aligned(16))) bf16_t Vs[2 * 4096];  // 16 KB -> 32 KB
  // bid bits: [Tb'(4)][c(3)][x(3)] -> head = x*8+c (XCD-grouped), Tb = 15-Tb' (LPT)
  const int bid = blockIdx.x;
  const int head = ((bid & 7) << 3) | ((bid >> 3) & 7);
  const int Tb = 15 - (bid >> 6);
  const int b = head >> 5, h = head & 31;
  const int kvh = b * KV_ + (h >> 2);
  const int tid = threadIdx.x;
  const int wave = tid >> 6, lane = tid & 63;
  const int cq = lane & 31, hh = lane >> 5;
  const int sw7 = lane & 7;
  const int q0 = Tb * 128 + wave * 32, qg = q0 + cq;
  const int nt = 2 * Tb + 2;            // 64-k tiles staged by the block
  const int last = 2 * Tb + (wave >> 1);  // this wave's diag tile

  const bf16_t* kb = Kc + (size_t)kvh * S_ * HD_;
  const bf16_t* vb = Vt + (size_t)kvh * HD_ * S_;

  // Q fragments (B operand): lane holds Q[q0+cq][ds*16 + hh*8 .. +8]
  const bf16_t* qp = Q + ((size_t)head * S_ + qg) * HD_ + hh * 8;
  short8 qf[4];
#pragma unroll
  for (int ds = 0; ds < 4; ds++) qf[ds] = *(const short8*)(qp + ds * 16);

  floatx16 o0 = {}, o1 = {};
  float m = -1e30f, l = 0.f;            // l kept per-half; merged at store

  stage64_4w(kb, vb, Ks, Vs, tid);

  for (int kt = 0; kt < nt; kt++) {
    __syncthreads();
    if (kt + 1 < nt)
      stage64_4w(kb + (size_t)(kt + 1) * 64 * HD_, vb + (kt + 1) * 64,
                 Ks + ((kt + 1) & 1) * 4096, Vs + ((kt + 1) & 1) * 4096, tid);
    if (kt > last) continue;            // wave-uniform; barriers still honored
    const bf16_t* Kt = Ks + (kt & 1) * 4096;
    const bf16_t* Vc = Vs + (kt & 1) * 4096;

    // QK^T: S^T[k][q], two 32-k subtiles, K summed over 4 d-slices
    floatx16 s0 = {}, s1 = {};
    __builtin_amdgcn_s_setprio(1);
#pragma unroll
    for (int ds = 0; ds < 4; ds++) {
      const int slot = (((ds * 2 + hh) ^ sw7) * 8);
      const short8 k0 = *(const short8*)&Kt[cq * 64 + slot];
      const short8 k1 = *(const short8*)&Kt[(32 + cq) * 64 + slot];
      s0 = __builtin_amdgcn_mfma_f32_32x32x16_bf16(k0, qf[ds], s0, 0, 0, 0);
      s1 = __builtin_amdgcn_mfma_f32_32x32x16_bf16(k1, qf[ds], s1, 0, 0, 0);
    }
    __builtin_amdgcn_s_setprio(0);

    // causal mask on this wave's diag tile
    if (kt == last) {
      const int kbase = kt * 64 + 4 * hh;
#pragma unroll
      for (int r = 0; r < 16; r++) {
        const int kg = kbase + (r & 3) + 8 * (r >> 2);
        s0[r] = (kg <= qg) ? s0[r] : -1e30f;
        s1[r] = (kg + 32 <= qg) ? s1[r] : -1e30f;
      }
    }

    // row max: lane-local tree over 32 + cross-half merge
    float t[8];
#pragma unroll
    for (int i = 0; i < 8; i++)
      t[i] = fmaxf(fmaxf(s0[i], s0[i + 8]), fmaxf(s1[i], s1[i + 8]));
#pragma unroll
    for (int st = 4; st >= 1; st >>= 1)
#pragma unroll
      for (int i = 0; i < st; i++) t[i] = fmaxf(t[i], t[i + st]);
    float mx = t[0];
    mx = fmaxf(mx, __shfl_xor(mx, 32, 64));

    // defer-max (T13): only rescale when max grew by > 8 (exp2 domain)
    if (!__all(mx <= m + 8.0f)) {
      const float mn = fmaxf(m, mx);
      const float a = fexp2(m - mn);
      l *= a;
#pragma unroll
      for (int i = 0; i < 16; i++) { o0[i] *= a; o1[i] *= a; }
      m = mn;
    }

    // P = exp2(S - m), row-sum (per-half partial)
#pragma unroll
    for (int i = 0; i < 16; i++) {
      s0[i] = fexp2(s0[i] - m);
      s1[i] = fexp2(s1[i] - m);
    }
    float u[8];
#pragma unroll
    for (int i = 0; i < 8; i++)
      u[i] = (s0[i] + s0[i + 8]) + (s1[i] + s1[i + 8]);
#pragma unroll
    for (int st = 4; st >= 1; st >>= 1)
#pragma unroll
      for (int i = 0; i < st; i++) u[i] += u[i + st];
    l += u[0];

    // P -> bf16 B-fragments in-register (16 cvt_pk + 8 half-swaps)
    short8 pf[4];
    build_pfrag(s0, pf[0], pf[1]);
    build_pfrag(s1, pf[2], pf[3]);

    // PV: O^T[d][q] += V^T x P^T, two 32-d subtiles, 4 k-slices
    __builtin_amdgcn_s_setprio(1);
#pragma unroll
    for (int ks = 0; ks < 4; ks++) {
      const int slot = (((ks * 2 + hh) ^ sw7) * 8);
      const short8 v0 = *(const short8*)&Vc[cq * 64 + slot];
      const short8 v1 = *(const short8*)&Vc[(32 + cq) * 64 + slot];
      o0 = __builtin_amdgcn_mfma_f32_32x32x16_bf16(v0, pf[ks], o0, 0, 0, 0);
      o1 = __builtin_amdgcn_mfma_f32_32x32x16_bf16(v1, pf[ks], o1, 0, 0, 0);
    }
    __builtin_amdgcn_s_setprio(0);
  }

  // epilogue: merge per-half l, normalize, store
  const float lt = l + __shfl_xor(l, 32, 64);
  const float li = 1.f / lt;
  bf16_t* obp = O + ((size_t)b * S_ + qg) * (H_ * HD_) + h * HD_ + hh * 4;
#pragma unroll
  for (int rq = 0; rq < 4; rq++) {
    uint2 w0;
    w0.x = pk_bf16(o0[4 * rq] * li, o0[4 * rq + 1] * li);
    w0.y = pk_bf16(o0[4 * rq + 2] * li, o0[4 * rq + 3] * li);
    *(uint2*)(obp + rq * 8) = w0;
    uint2 w1;
    w1.x = pk_bf16(o1[4 * rq] * li, o1[4 * rq + 1] * li);
    w1.y = pk_bf16(o1[4 * rq + 2] * li, o1[4 * rq + 3] * li);
    *(uint2*)(obp + 32 + rq * 8) = w1;
  }
}

extern "C" void kernel_launch(void* const* d_in, const int* in_sizes, int n_in,
                              void* d_out, int out_size, void* d_ws, size_t ws_size,
                              hipStream_t stream) {
  const float* x    = (const float*)d_in[0];
  const float* cs   = (const float*)d_in[1];
  const float* sn   = (const float*)d_in[2];
  const float* wqkv = (const float*)d_in[3];
  const float* wout = (const float*)d_in[4];
  float* out = (float*)d_out;

  char* ws = (char*)d_ws;
  bf16_t*  xb    = (bf16_t*)(ws);                 // 16,777,216 B
  bf16_t*  wqkvb = (bf16_t*)(ws + 16777216);      // 12,582,912 B
  bf16_t*  woutb = (bf16_t*)(ws + 29360128);      //  8,388,608 B
  bf16_t*  qb    = (bf16_t*)(ws + 37748736);      // 16,777,216 B
  bf16_t*  kb    = (bf16_t*)(ws + 54525952);      //  4,194,304 B
  bf16_t*  vtb   = (bf16_t*)(ws + 58720256);      //  4,194,304 B
  bf16_t*  attnb = (bf16_t*)(ws + 62914560);      // 16,777,216 B
  unsigned* tab  = (unsigned*)(ws + 79691776);    //    524,288 B (total ~80 MB)

  prep<<<18944, 256, 0, stream>>>(x, xb, wqkv, wqkvb, wout, woutb, cs, sn, tab);
  gemm_qkv<<<dim3(24, 32), 256, 0, stream>>>(xb, wqkvb, tab, qb, kb, vtb);
  flash_attn<<<1024, 256, 0, stream>>>(qb, kb, vtb, attnb);
  gemm_bt<<<dim3(16, 32), 256, 0, stream>>>(attnb, woutb, out, 4096, 2048, 2048);
}

// Round 7
// 274.323 us; speedup vs baseline: 1.3053x; 1.0649x over previous
//
#include <hip/hip_runtime.h>
#include <hip/hip_fp16.h>

#define B_ 2
#define S_ 2048
#define D_ 2048
#define H_ 32
#define KV_ 8
#define HD_ 64

typedef unsigned short bf16_t;
typedef __attribute__((ext_vector_type(8))) short short8;
typedef __attribute__((ext_vector_type(4))) float floatx4;
typedef __attribute__((ext_vector_type(16))) float floatx16;

__device__ __forceinline__ bf16_t f2bf(float f) {
  union { float f; unsigned u; } c; c.f = f;
  unsigned u = c.u;
  u += 0x7fffu + ((u >> 16) & 1u);          // round-to-nearest-even
  return (bf16_t)(u >> 16);
}

__device__ __forceinline__ unsigned pk_bf16(float a, float b) {
#if __has_builtin(__builtin_amdgcn_cvt_pk_bf16_f32)
  auto v = __builtin_amdgcn_cvt_pk_bf16_f32(a, b);
  unsigned u; __builtin_memcpy(&u, &v, 4); return u;
#else
  return (unsigned)f2bf(a) | ((unsigned)f2bf(b) << 16);
#endif
}

__device__ __forceinline__ float fexp2(float x) {
#if __has_builtin(__builtin_amdgcn_exp2f)
  return __builtin_amdgcn_exp2f(x);
#else
  return exp2f(x);
#endif
}

__device__ __forceinline__ void load_lds16(const void* g, void* l) {
  __builtin_amdgcn_global_load_lds(
      (const __attribute__((address_space(1))) void*)g,
      (__attribute__((address_space(3))) void*)l, 16, 0, 0);
}

// ---------------- prep: fp32->bf16 casts + packed fp16 rope table ----------------
__device__ __forceinline__ void cvt4(const float* __restrict__ in,
                                     bf16_t* __restrict__ out, int i) {
  float4 v = ((const float4*)in)[i];
  ushort4 o;
  o.x = f2bf(v.x); o.y = f2bf(v.y); o.z = f2bf(v.z); o.w = f2bf(v.w);
  ((ushort4*)out)[i] = o;
}

__global__ __launch_bounds__(256) void prep(
    const float* __restrict__ x, bf16_t* __restrict__ xb,
    const float* __restrict__ wqkv, bf16_t* __restrict__ wqkvb,
    const float* __restrict__ wout, bf16_t* __restrict__ woutb,
    const float* __restrict__ cs, const float* __restrict__ sn,
    unsigned* __restrict__ tab) {
  const int bid = blockIdx.x;
  if (bid < 8192) {
    cvt4(x, xb, bid * 256 + threadIdx.x);
  } else if (bid < 14336) {
    cvt4(wqkv, wqkvb, (bid - 8192) * 256 + threadIdx.x);
  } else if (bid < 18432) {
    cvt4(wout, woutb, (bid - 14336) * 256 + threadIdx.x);
  } else {
    const int i = (bid - 18432) * 256 + threadIdx.x;   // 131072 entries
    __half2 h = __floats2half2_rn(cs[i], sn[i]);
    unsigned u; __builtin_memcpy(&u, &h, 4);
    tab[i] = u;
  }
}

// ---------------- bf16 GEMM: C[M,N] = A[M,K] * B^T (f32 out) ----------------
// BK=64 (half the barrier drains of BK=32), XOR-swizzled LDS:
// LDS[row][slot] = global[row][slot ^ (row&7)] (slot = 16B chunk, 8/row).
__global__ __launch_bounds__(256) void gemm_bt(
    const bf16_t* __restrict__ A, const bf16_t* __restrict__ Bm,
    float* __restrict__ C, int M, int N, int K) {
  __shared__ __attribute__((aligned(16))) bf16_t As[128 * 64];  // 16 KB
  __shared__ __attribute__((aligned(16))) bf16_t Bs[128 * 64];  // 16 KB
  const int tid = threadIdx.x;
  const int lane = tid & 63;
  const int wave = tid >> 6;
  const int bm = blockIdx.y * 128, bn = blockIdx.x * 128;
  const int wm = (wave >> 1) * 64, wn = (wave & 1) * 64;
  const int lr = lane & 15, quad = lane >> 4;

  floatx4 acc[4][4] = {};

  const bf16_t* Ab = A + (size_t)bm * K;
  const bf16_t* Bb = Bm + (size_t)bn * K;

  for (int k0 = 0; k0 < K; k0 += 64) {
    __syncthreads();
#pragma unroll
    for (int p = 0; p < 4; p++) {
      const int idx = p * 256 + tid;
      const int row = idx >> 3, sc = idx & 7;
      const int gc = sc ^ (row & 7);
      load_lds16(Ab + (size_t)row * K + k0 + gc * 8, &As[idx * 8]);
      load_lds16(Bb + (size_t)row * K + k0 + gc * 8, &Bs[idx * 8]);
    }
    __syncthreads();

#pragma unroll
    for (int ks = 0; ks < 2; ks++) {
      short8 af[4], bfr[4];
#pragma unroll
      for (int i = 0; i < 4; i++) {
        const int ra = wm + i * 16 + lr;
        const int rb = wn + i * 16 + lr;
        af[i]  = *(const short8*)&As[ra * 64 + (((ks * 4 + quad) ^ (ra & 7)) * 8)];
        bfr[i] = *(const short8*)&Bs[rb * 64 + (((ks * 4 + quad) ^ (rb & 7)) * 8)];
      }
#pragma unroll
      for (int mi = 0; mi < 4; mi++)
#pragma unroll
        for (int ni = 0; ni < 4; ni++)
          acc[mi][ni] = __builtin_amdgcn_mfma_f32_16x16x32_bf16(af[mi], bfr[ni], acc[mi][ni], 0, 0, 0);
    }
  }

#pragma unroll
  for (int mi = 0; mi < 4; mi++) {
    const int row = bm + wm + mi * 16 + quad * 4;
#pragma unroll
    for (int ni = 0; ni < 4; ni++) {
      const int col = bn + wn + ni * 16 + lr;
      float* cp = C + (size_t)row * N + col;
#pragma unroll
      for (int r = 0; r < 4; r++) cp[(size_t)r * N] = acc[mi][ni][r];
    }
  }
}

// ---------------- fused QKV GEMM + RoPE (fp16 table) + repack ----------------
// Ts transpose scratch now aliases As/Bs (dead after the K-loop): LDS 50->32 KB
// => 4 blocks/CU (VGPR 112 allows 4 waves/SIMD). One uniform __syncthreads()
// after the K-loop retires all As/Bs reads before reuse.
__global__ __launch_bounds__(256, 4) void gemm_qkv(
    const bf16_t* __restrict__ A, const bf16_t* __restrict__ Bm,
    const unsigned* __restrict__ tab,
    bf16_t* __restrict__ q, bf16_t* __restrict__ k, bf16_t* __restrict__ vt) {
  const int K = 2048;
  __shared__ __attribute__((aligned(16))) bf16_t As[128 * 64];  // 16 KB
  __shared__ __attribute__((aligned(16))) bf16_t Bs[128 * 64];  // 16 KB
  const int tid = threadIdx.x;
  const int lane = tid & 63;
  const int wave = tid >> 6;
  const int bm = blockIdx.y * 128, bn = blockIdx.x * 128;
  const int wm = (wave >> 1) * 64, wn = (wave & 1) * 64;
  const int lr = lane & 15, quad = lane >> 4;

  floatx4 acc[4][4] = {};

  const bf16_t* Ab = A + (size_t)bm * K;
  const bf16_t* Bb = Bm + (size_t)bn * K;

  for (int k0 = 0; k0 < K; k0 += 64) {
    __syncthreads();
#pragma unroll
    for (int p = 0; p < 4; p++) {
      const int idx = p * 256 + tid;
      const int row = idx >> 3, sc = idx & 7;
      const int gc = sc ^ (row & 7);
      load_lds16(Ab + (size_t)row * K + k0 + gc * 8, &As[idx * 8]);
      load_lds16(Bb + (size_t)row * K + k0 + gc * 8, &Bs[idx * 8]);
    }
    __syncthreads();

#pragma unroll
    for (int ks = 0; ks < 2; ks++) {
      short8 af[4], bfr[4];
#pragma unroll
      for (int i = 0; i < 4; i++) {
        const int ra = wm + i * 16 + lr;
        const int rb = wn + i * 16 + lr;
        af[i]  = *(const short8*)&As[ra * 64 + (((ks * 4 + quad) ^ (ra & 7)) * 8)];
        bfr[i] = *(const short8*)&Bs[rb * 64 + (((ks * 4 + quad) ^ (rb & 7)) * 8)];
      }
#pragma unroll
      for (int mi = 0; mi < 4; mi++)
#pragma unroll
        for (int ni = 0; ni < 4; ni++)
          acc[mi][ni] = __builtin_amdgcn_mfma_f32_16x16x32_bf16(af[mi], bfr[ni], acc[mi][ni], 0, 0, 0);
    }
  }

  __syncthreads();   // uniform: As/Bs reads retired; safe to reuse as scratch

  const int f0 = bn + wn;              // wave-uniform feature base (multiple of 64)
  const int srow0 = bm + wm;
  const int bb = srow0 >> 11, s0 = srow0 & 2047;

  if (f0 < 2560) {                     // Q or K head: in-register rope
    const bool isq = (f0 < 2048);
    const float scale = isq ? 0.18033688011f : 1.0f;   // 0.125 * log2(e)
    bf16_t* dst = isq ? (q + (size_t)(bb * H_ + (f0 >> 6)) * S_ * HD_)
                      : (k + (size_t)(bb * KV_ + ((f0 - 2048) >> 6)) * S_ * HD_);
#pragma unroll
    for (int mi = 0; mi < 4; mi++) {
#pragma unroll
      for (int r = 0; r < 4; r++) {
        const int sr = s0 + mi * 16 + quad * 4 + r;
        const unsigned* tp = tab + (size_t)sr * HD_;
        bf16_t* drow = dst + (size_t)sr * HD_;
#pragma unroll
        for (int ni = 0; ni < 4; ni++) {
          const int d = ni * 16 + lr;
          const unsigned w = tp[d];
          __half2 h2; __builtin_memcpy(&h2, &w, 4);
          const float2 cf = __half22float2(h2);
          const float t = acc[mi][ni][r];
          const float oth = acc[mi][ni ^ 2][r];
          const float rot = (ni < 2) ? -oth : oth;   // d<32 iff ni<2
          drow[d] = f2bf((t * cf.x + rot * cf.y) * scale);
        }
      }
    }
  } else {                             // V head: 2-pass transpose via aliased scratch
    const int hv = (f0 - 2560) >> 6;
    // per-wave 4608 B region: waves 0-1 in As, waves 2-3 in Bs (16B-aligned:
    // 2304 elem * 2 B = 4608 = 288*16; row stride 72 elem * 2 B = 144 = 9*16)
    bf16_t* ts = (wave < 2) ? (As + wave * 2304) : (Bs + (wave - 2) * 2304);
    const int rl = lane >> 1, hf = lane & 1;
#pragma unroll
    for (int p = 0; p < 2; p++) {
#pragma unroll
      for (int nn = 0; nn < 2; nn++) {
        const int ni = 2 * p + nn;
#pragma unroll
        for (int mi = 0; mi < 4; mi++) {
          uint2 pw;
          pw.x = pk_bf16(acc[mi][ni][0], acc[mi][ni][1]);
          pw.y = pk_bf16(acc[mi][ni][2], acc[mi][ni][3]);
          *(uint2*)&ts[(nn * 16 + lr) * 72 + mi * 16 + quad * 4] = pw;
        }
      }
      // same-wave RAW/WAR: DS pipe is in-order per wave, compiler emits lgkmcnt
      bf16_t* vrow = vt + ((size_t)(bb * KV_ + hv) * HD_ + p * 32 + rl) * S_ + s0 + hf * 32;
#pragma unroll
      for (int j = 0; j < 4; j++)
        *(short8*)(vrow + j * 8) = *(const short8*)&ts[rl * 72 + hf * 32 + j * 8];
    }
  }
}

// ---------------- flash attention v7: staged, 4-wave blocks, KVBLK=64 ----------------
// Block owns 128 q-rows (4 waves x 32); K/V staged cooperatively into 32 KB LDS,
// double-buffered, swizzle convention LDS[r][sc]=g[r][sc^(r&7)].
// Grid 1024 blocks x 4 waves; LPT (heavy Tb first) + XCD head-grouping.

__device__ __forceinline__ void stage64_4w(const bf16_t* __restrict__ gk,
                                           const bf16_t* __restrict__ gv,
                                           bf16_t* kbuf, bf16_t* vbuf, int tid) {
#pragma unroll
  for (int j = 0; j < 2; j++) {
    const int idx = j * 256 + tid;      // 512 chunks of 16B per 64x64 tile
    const int row = idx >> 3;
    const int sc  = idx & 7;
    const int gc  = sc ^ (row & 7);
    load_lds16(gk + (size_t)row * HD_ + gc * 8, kbuf + idx * 8);
    load_lds16(gv + (size_t)row * S_  + gc * 8, vbuf + idx * 8);
  }
}

// halves-exchange: x = [a.lo | b.lo], y = [a.hi | b.hi] (lanes 0-31 | 32-63)
__device__ __forceinline__ void hswap(unsigned a, unsigned b, unsigned& x, unsigned& y) {
#if __has_builtin(__builtin_amdgcn_permlane32_swap)
  auto r = __builtin_amdgcn_permlane32_swap(a, b, false, false);
  x = (unsigned)r[0]; y = (unsigned)r[1];
#else
  const unsigned pa = (unsigned)__shfl_xor((int)a, 32, 64);
  const unsigned pb = (unsigned)__shfl_xor((int)b, 32, 64);
  const bool hi = (threadIdx.x & 32) != 0;
  x = hi ? pb : a;
  y = hi ? b : pa;
#endif
}

// one k-subtile (32 k) of P in lane regs -> two PV B-fragments (k-slices of 16)
__device__ __forceinline__ void build_pfrag(const floatx16& p, short8& f0, short8& f1) {
  unsigned w[8];
  const unsigned c01 = pk_bf16(p[0], p[1]);
  const unsigned c45 = pk_bf16(p[4], p[5]);
  const unsigned c23 = pk_bf16(p[2], p[3]);
  const unsigned c67 = pk_bf16(p[6], p[7]);
  hswap(c01, c45, w[0], w[2]);
  hswap(c23, c67, w[1], w[3]);
  const unsigned d01 = pk_bf16(p[8], p[9]);
  const unsigned d45 = pk_bf16(p[12], p[13]);
  const unsigned d23 = pk_bf16(p[10], p[11]);
  const unsigned d67 = pk_bf16(p[14], p[15]);
  hswap(d01, d45, w[4], w[6]);
  hswap(d23, d67, w[5], w[7]);
  __builtin_memcpy(&f0, &w[0], 16);
  __builtin_memcpy(&f1, &w[4], 16);
}

__global__ __launch_bounds__(256, 2) void flash_attn(
    const bf16_t* __restrict__ Q,   // [B*H, S, 64] (pre-scaled by 0.125*log2e)
    const bf16_t* __restrict__ Kc,  // [B*KV, S, 64]
    const bf16_t* __restrict__ Vt,  // [B*KV, 64, S]
    bf16_t* __restrict__ O) {       // [B, S, H*64]
  __shared__ __attribute__((aligned(16))) bf16_t Ks[2 * 4096];  // 16 KB
  __shared__ __attribute__((aligned(16))) bf16_t Vs[2 * 4096];  // 16 KB -> 32 KB
  // bid bits: [Tb'(4)][c(3)][x(3)] -> head = x*8+c (XCD-grouped), Tb = 15-Tb' (LPT)
  const int bid = blockIdx.x;
  const int head = ((bid & 7) << 3) | ((bid >> 3) & 7);
  const int Tb = 15 - (bid >> 6);
  const int b = head >> 5, h = head & 31;
  const int kvh = b * KV_ + (h >> 2);
  const int tid = threadIdx.x;
  const int wave = tid >> 6, lane = tid & 63;
  const int cq = lane & 31, hh = lane >> 5;
  const int sw7 = lane & 7;
  const int q0 = Tb * 128 + wave * 32, qg = q0 + cq;
  const int nt = 2 * Tb + 2;            // 64-k tiles staged by the block
  const int last = 2 * Tb + (wave >> 1);  // this wave's diag tile

  const bf16_t* kb = Kc + (size_t)kvh * S_ * HD_;
  const bf16_t* vb = Vt + (size_t)kvh * HD_ * S_;

  // Q fragments (B operand): lane holds Q[q0+cq][ds*16 + hh*8 .. +8]
  const bf16_t* qp = Q + ((size_t)head * S_ + qg) * HD_ + hh * 8;
  short8 qf[4];
#pragma unroll
  for (int ds = 0; ds < 4; ds++) qf[ds] = *(const short8*)(qp + ds * 16);

  floatx16 o0 = {}, o1 = {};
  float m = -1e30f, l = 0.f;            // l kept per-half; merged at store

  stage64_4w(kb, vb, Ks, Vs, tid);

  for (int kt = 0; kt < nt; kt++) {
    __syncthreads();
    if (kt + 1 < nt)
      stage64_4w(kb + (size_t)(kt + 1) * 64 * HD_, vb + (kt + 1) * 64,
                 Ks + ((kt + 1) & 1) * 4096, Vs + ((kt + 1) & 1) * 4096, tid);
    if (kt > last) continue;            // wave-uniform; barriers still honored
    const bf16_t* Kt = Ks + (kt & 1) * 4096;
    const bf16_t* Vc = Vs + (kt & 1) * 4096;

    // QK^T: S^T[k][q], two 32-k subtiles, K summed over 4 d-slices
    floatx16 s0 = {}, s1 = {};
    __builtin_amdgcn_s_setprio(1);
#pragma unroll
    for (int ds = 0; ds < 4; ds++) {
      const int slot = (((ds * 2 + hh) ^ sw7) * 8);
      const short8 k0 = *(const short8*)&Kt[cq * 64 + slot];
      const short8 k1 = *(const short8*)&Kt[(32 + cq) * 64 + slot];
      s0 = __builtin_amdgcn_mfma_f32_32x32x16_bf16(k0, qf[ds], s0, 0, 0, 0);
      s1 = __builtin_amdgcn_mfma_f32_32x32x16_bf16(k1, qf[ds], s1, 0, 0, 0);
    }
    __builtin_amdgcn_s_setprio(0);

    // causal mask on this wave's diag tile
    if (kt == last) {
      const int kbase = kt * 64 + 4 * hh;
#pragma unroll
      for (int r = 0; r < 16; r++) {
        const int kg = kbase + (r & 3) + 8 * (r >> 2);
        s0[r] = (kg <= qg) ? s0[r] : -1e30f;
        s1[r] = (kg + 32 <= qg) ? s1[r] : -1e30f;
      }
    }

    // row max: lane-local tree over 32 + cross-half merge
    float t[8];
#pragma unroll
    for (int i = 0; i < 8; i++)
      t[i] = fmaxf(fmaxf(s0[i], s0[i + 8]), fmaxf(s1[i], s1[i + 8]));
#pragma unroll
    for (int st = 4; st >= 1; st >>= 1)
#pragma unroll
      for (int i = 0; i < st; i++) t[i] = fmaxf(t[i], t[i + st]);
    float mx = t[0];
    mx = fmaxf(mx, __shfl_xor(mx, 32, 64));

    // defer-max (T13): only rescale when max grew by > 8 (exp2 domain)
    if (!__all(mx <= m + 8.0f)) {
      const float mn = fmaxf(m, mx);
      const float a = fexp2(m - mn);
      l *= a;
#pragma unroll
      for (int i = 0; i < 16; i++) { o0[i] *= a; o1[i] *= a; }
      m = mn;
    }

    // P = exp2(S - m), row-sum (per-half partial)
#pragma unroll
    for (int i = 0; i < 16; i++) {
      s0[i] = fexp2(s0[i] - m);
      s1[i] = fexp2(s1[i] - m);
    }
    float u[8];
#pragma unroll
    for (int i = 0; i < 8; i++)
      u[i] = (s0[i] + s0[i + 8]) + (s1[i] + s1[i + 8]);
#pragma unroll
    for (int st = 4; st >= 1; st >>= 1)
#pragma unroll
      for (int i = 0; i < st; i++) u[i] += u[i + st];
    l += u[0];

    // P -> bf16 B-fragments in-register (16 cvt_pk + 8 half-swaps)
    short8 pf[4];
    build_pfrag(s0, pf[0], pf[1]);
    build_pfrag(s1, pf[2], pf[3]);

    // PV: O^T[d][q] += V^T x P^T, two 32-d subtiles, 4 k-slices
    __builtin_amdgcn_s_setprio(1);
#pragma unroll
    for (int ks = 0; ks < 4; ks++) {
      const int slot = (((ks * 2 + hh) ^ sw7) * 8);
      const short8 v0 = *(const short8*)&Vc[cq * 64 + slot];
      const short8 v1 = *(const short8*)&Vc[(32 + cq) * 64 + slot];
      o0 = __builtin_amdgcn_mfma_f32_32x32x16_bf16(v0, pf[ks], o0, 0, 0, 0);
      o1 = __builtin_amdgcn_mfma_f32_32x32x16_bf16(v1, pf[ks], o1, 0, 0, 0);
    }
    __builtin_amdgcn_s_setprio(0);
  }

  // epilogue: merge per-half l, normalize, store
  const float lt = l + __shfl_xor(l, 32, 64);
  const float li = 1.f / lt;
  bf16_t* obp = O + ((size_t)b * S_ + qg) * (H_ * HD_) + h * HD_ + hh * 4;
#pragma unroll
  for (int rq = 0; rq < 4; rq++) {
    uint2 w0;
    w0.x = pk_bf16(o0[4 * rq] * li, o0[4 * rq + 1] * li);
    w0.y = pk_bf16(o0[4 * rq + 2] * li, o0[4 * rq + 3] * li);
    *(uint2*)(obp + rq * 8) = w0;
    uint2 w1;
    w1.x = pk_bf16(o1[4 * rq] * li, o1[4 * rq + 1] * li);
    w1.y = pk_bf16(o1[4 * rq + 2] * li, o1[4 * rq + 3] * li);
    *(uint2*)(obp + 32 + rq * 8) = w1;
  }
}

extern "C" void kernel_launch(void* const* d_in, const int* in_sizes, int n_in,
                              void* d_out, int out_size, void* d_ws, size_t ws_size,
                              hipStream_t stream) {
  const float* x    = (const float*)d_in[0];
  const float* cs   = (const float*)d_in[1];
  const float* sn   = (const float*)d_in[2];
  const float* wqkv = (const float*)d_in[3];
  const float* wout = (const float*)d_in[4];
  float* out = (float*)d_out;

  char* ws = (char*)d_ws;
  bf16_t*  xb    = (bf16_t*)(ws);                 // 16,777,216 B
  bf16_t*  wqkvb = (bf16_t*)(ws + 16777216);      // 12,582,912 B
  bf16_t*  woutb = (bf16_t*)(ws + 29360128);      //  8,388,608 B
  bf16_t*  qb    = (bf16_t*)(ws + 37748736);      // 16,777,216 B
  bf16_t*  kb    = (bf16_t*)(ws + 54525952);      //  4,194,304 B
  bf16_t*  vtb   = (bf16_t*)(ws + 58720256);      //  4,194,304 B
  bf16_t*  attnb = (bf16_t*)(ws + 62914560);      // 16,777,216 B
  unsigned* tab  = (unsigned*)(ws + 79691776);    //    524,288 B (total ~80 MB)

  prep<<<18944, 256, 0, stream>>>(x, xb, wqkv, wqkvb, wout, woutb, cs, sn, tab);
  gemm_qkv<<<dim3(24, 32), 256, 0, stream>>>(xb, wqkvb, tab, qb, kb, vtb);
  flash_attn<<<1024, 256, 0, stream>>>(qb, kb, vtb, attnb);
  gemm_bt<<<dim3(16, 32), 256, 0, stream>>>(attnb, woutb, out, 4096, 2048, 2048);
}